// Round 11
// baseline (156.413 us; speedup 1.0000x reference)
//
#include <hip/hip_runtime.h>

#define D_F 128
#define D_H 512
#define SHS 520   // sH row stride (bf16 elems): 1040 B, 16B-aligned

typedef short v8s __attribute__((ext_vector_type(8)));
typedef float v4f __attribute__((ext_vector_type(4)));
typedef _Float16 v2h __attribute__((ext_vector_type(2)));

__device__ inline unsigned short f2bf(float f) {
    unsigned u = __float_as_uint(f);
    unsigned r = (u + 0x7fffu + ((u >> 16) & 1u)) >> 16;   // RNE
    return (unsigned short)r;
}
__device__ inline v2h bch(unsigned x) { return __builtin_bit_cast(v2h, x); }

// ---------------------------------------------------------------------------
// prep: weight conversion (all blocks) + init cumsums/zeros/counter (block 0)
// ---------------------------------------------------------------------------
__global__ __launch_bounds__(256) void prep_kernel(
    const float* __restrict__ W1, const float* __restrict__ W2,
    const int* __restrict__ n_node, const int* __restrict__ n_edge,
    unsigned short* __restrict__ W1T, unsigned short* __restrict__ W2T,
    int* __restrict__ ec, int* __restrict__ nid,
    float* __restrict__ ew, float* __restrict__ ga, int* __restrict__ dctr,
    int G, int E)
{
    if (blockIdx.x == 0) {
        __shared__ int sne[512];
        __shared__ int snn[512];
        const int t = threadIdx.x;
        if (t == 0) *dctr = 0;
        for (int g = t; g < G; g += 256) { sne[g] = n_edge[g]; snn[g] = n_node[g]; }
        __syncthreads();
        for (int g = t; g < G; g += 256) {
            int se = 0, sn = 0;
            for (int k = 0; k < g; ++k)  se += sne[k];
            for (int k = 0; k <= g; ++k) sn += snn[k];
            ec[g]  = se;
            nid[g] = sn - 1;
            ew[g] = 0.f;
            ga[g] = 0.f;
            if (g == G - 1) {
                int tot = se + sne[g];
                ec[G] = tot > E ? tot : E;
            }
        }
    }
    int i = blockIdx.x * 256 + threadIdx.x;
    if (i < D_F * D_H) {
        int n = i >> 7, k = i & (D_F - 1);        // W1T[n][k] = W1[k][n]
        W1T[i] = f2bf(W1[k * D_H + n]);
        int n2 = i >> 9, k2 = i & (D_H - 1);      // W2T[n2][k2] = W2[k2][n2]
        W2T[i] = f2bf(W2[k2 * D_F + n2]);
    }
}

// ---------------------------------------------------------------------------
// Fused MLP via MFMA (bf16 weights, fp16 output h): 16 rows / block, 8 waves
// splitting the n-dimension (5000 waves).
// ---------------------------------------------------------------------------
__global__ __launch_bounds__(512) void mlp_mfma_kernel(
    const float* __restrict__ nodes,
    const unsigned short* __restrict__ W1T, const float* __restrict__ b1,
    const unsigned short* __restrict__ W2T, const float* __restrict__ b2,
    _Float16* __restrict__ hh, int N)
{
    __shared__ unsigned short sH[16 * SHS];   // 16.6 KB

    const int t    = threadIdx.x;
    const int wave = t >> 6;        // 0..7
    const int lane = t & 63;
    const int li   = lane & 15;
    const int quad = lane >> 4;
    const int row0 = blockIdx.x * 16;

    // A fragments for GEMM1 (same 16 rows for all 8 waves; L1-served)
    v8s a1[4];
    {
        int r = min(row0 + li, N - 1);
        const float* xp = nodes + (size_t)r * D_F + quad * 8;
        #pragma unroll
        for (int ks = 0; ks < 4; ++ks) {
            float4 f0 = *(const float4*)(xp + ks * 32);
            float4 f1 = *(const float4*)(xp + ks * 32 + 4);
            v8s v;
            v[0] = (short)f2bf(f0.x); v[1] = (short)f2bf(f0.y);
            v[2] = (short)f2bf(f0.z); v[3] = (short)f2bf(f0.w);
            v[4] = (short)f2bf(f1.x); v[5] = (short)f2bf(f1.y);
            v[6] = (short)f2bf(f1.z); v[7] = (short)f2bf(f1.w);
            a1[ks] = v;
        }
    }

    // GEMM1: this wave covers hidden cols [wave*64, wave*64+64)
    #pragma unroll 2
    for (int jj = 0; jj < 4; ++jj) {
        const int n0 = (wave * 4 + jj) * 16;
        const unsigned short* wp = W1T + (size_t)(n0 + li) * D_F + quad * 8;
        v4f acc = {0.f, 0.f, 0.f, 0.f};
        #pragma unroll
        for (int ks = 0; ks < 4; ++ks) {
            v8s b = *(const v8s*)(wp + ks * 32);
            acc = __builtin_amdgcn_mfma_f32_16x16x32_bf16(a1[ks], b, acc, 0, 0, 0);
        }
        float bias = b1[n0 + li];
        #pragma unroll
        for (int r = 0; r < 4; ++r) {
            float hv = fmaxf(acc[r] + bias, 0.f);
            int m = quad * 4 + r;                 // C layout: row = quad*4+reg
            sH[m * SHS + n0 + li] = f2bf(hv);     // col = li
        }
    }
    __syncthreads();

    // A fragments for GEMM2 from LDS
    v8s aH[16];
    #pragma unroll
    for (int ks = 0; ks < 16; ++ks)
        aH[ks] = *(const v8s*)(sH + li * SHS + ks * 32 + quad * 8);

    // GEMM2: this wave covers output cols [wave*16, wave*16+16)
    {
        const int n0 = wave * 16;
        const unsigned short* wp = W2T + (size_t)(n0 + li) * D_H + quad * 8;
        v4f acc = {0.f, 0.f, 0.f, 0.f};
        #pragma unroll
        for (int kc = 0; kc < 2; ++kc) {
            v8s bb[8];
            #pragma unroll
            for (int u = 0; u < 8; ++u)
                bb[u] = *(const v8s*)(wp + (kc * 8 + u) * 32);
            #pragma unroll
            for (int u = 0; u < 8; ++u)
                acc = __builtin_amdgcn_mfma_f32_16x16x32_bf16(aH[kc * 8 + u], bb[u], acc, 0, 0, 0);
        }
        float bias = b2[n0 + li];
        #pragma unroll
        for (int r = 0; r < 4; ++r) {
            int grow = row0 + quad * 4 + r;
            if (grow < N)
                hh[(size_t)grow * D_F + n0 + li] = (_Float16)(acc[r] + bias);
        }
    }
}

// ---------------------------------------------------------------------------
// Edge stage: ONE exact 64-edge tile per wave (10000 waves). Lane l owns dims
// {2l,2l+1}; each gather covers ONE row (fully coalesced 256 B). __shfl
// broadcast, 16-edge batches. LDS-staged atomics. Last block finalizes via
// s_waitcnt ordering (NO __threadfence -> no L2 invalidate).
// ---------------------------------------------------------------------------
__global__ __launch_bounds__(256) void edge_kernel(
    const _Float16* __restrict__ hh, const float* __restrict__ wedge,
    const int* __restrict__ senders, const int* __restrict__ receivers,
    const int* __restrict__ ec, const int* __restrict__ nid,
    float* __restrict__ ew, float* __restrict__ ga, int* __restrict__ dctr,
    float* __restrict__ out, int E, int G)
{
    __shared__ int   sec[513];
    __shared__ float sga[512];
    __shared__ float sew[512];
    __shared__ int   sLast;
    __shared__ float sred[4];
    const int t = threadIdx.x;
    for (int i = t; i <= G; i += 256) sec[i] = ec[i];
    for (int i = t; i < G;  i += 256) { sga[i] = 0.f; sew[i] = 0.f; }
    __syncthreads();

    const unsigned* __restrict__ h32 = (const unsigned*)hh;   // row = 64 dwords
    const int lane = t & 63;
    const int wid  = blockIdx.x * 4 + (t >> 6);
    const int tb   = wid << 6;

    if (tb < E) {
        const int nt = min(64, E - tb);

        int gid;
        { int lo = 0, hi = G - 1;
          while (lo < hi) { int m = (lo + hi + 1) >> 1; if (sec[m] <= tb) lo = m; else hi = m - 1; }
          gid = lo; }

        const int ecl = min(tb + lane, E - 1);
        const bool vld = (tb + lane) < E;
        int   sv = __builtin_nontemporal_load(senders + ecl);
        int   rv = __builtin_nontemporal_load(receivers + ecl);
        float wv = vld ? __builtin_nontemporal_load(wedge + ecl) : 0.f;

        float accE = 0.f, accW = 0.f;

        if (nt == 64 && tb + 64 <= sec[gid + 1]) {
            // fast path: full tile in current segment
            #pragma unroll 1
            for (int i = 0; i < 64; i += 16) {
                unsigned a[16], b[16];
                int su[16], ru[16];
                #pragma unroll
                for (int u = 0; u < 16; ++u) {
                    su[u] = __shfl(sv, i + u);
                    ru[u] = __shfl(rv, i + u);
                }
                #pragma unroll
                for (int u = 0; u < 16; ++u) {
                    a[u] = h32[(unsigned)((su[u] << 6) | lane)];
                    b[u] = h32[(unsigned)((ru[u] << 6) | lane)];
                }
                #pragma unroll
                for (int u = 0; u < 16; ++u) {
                    float w = __shfl(wv, i + u);
                    v2h d  = bch(a[u]) - bch(b[u]);
                    float tt = __builtin_amdgcn_fdot2(d, d, 0.f, false);
                    accE = fmaf(w, tt, accE);
                }
            }
            accW = wv;   // own-lane weight; lane-sum = tile sum
            float rE = accE, rW = accW;
            #pragma unroll
            for (int m = 32; m > 0; m >>= 1) {
                rE += __shfl_xor(rE, m);
                rW += __shfl_xor(rW, m);
            }
            if (lane == 0) {
                atomicAdd(&sga[gid], rE);
                atomicAdd(&sew[gid], rW);
            }
        } else {
            // boundary/tail tile: per-edge with segment flushes
            for (int i = 0; i < nt; ++i) {
                int e = tb + i;
                while (e >= sec[gid + 1]) {
                    float rE = accE, rW = accW;
                    #pragma unroll
                    for (int m = 32; m > 0; m >>= 1) {
                        rE += __shfl_xor(rE, m);
                        rW += __shfl_xor(rW, m);
                    }
                    if (lane == 0 && (rE != 0.f || rW != 0.f)) {
                        atomicAdd(&sga[gid], rE);
                        atomicAdd(&sew[gid], rW);
                    }
                    accE = 0.f; accW = 0.f;
                    ++gid;
                }
                int   s = __shfl(sv, i);
                int   r = __shfl(rv, i);
                float w = __shfl(wv, i);
                unsigned a = h32[(unsigned)((s << 6) | lane)];
                unsigned b = h32[(unsigned)((r << 6) | lane)];
                v2h d = bch(a) - bch(b);
                float tt = __builtin_amdgcn_fdot2(d, d, 0.f, false);
                accE = fmaf(w, tt, accE);
                if (lane == 0) accW += w;
            }
            float rE = accE, rW = accW;
            #pragma unroll
            for (int m = 32; m > 0; m >>= 1) {
                rE += __shfl_xor(rE, m);
                rW += __shfl_xor(rW, m);
            }
            if (lane == 0 && (rE != 0.f || rW != 0.f)) {
                atomicAdd(&sga[gid], rE);
                atomicAdd(&sew[gid], rW);
            }
        }
    }

    __syncthreads();
    for (int g = t; g < G; g += 256) {
        float vg = sga[g], vw = sew[g];
        if (vg != 0.f || vw != 0.f) {
            atomicAdd(&ga[g], vg);
            atomicAdd(&ew[g], vw);
        }
    }

    // -------- fence-free last-block finalize -------------------------------
    // Drain this wave's flush atomics to the coherence point (s_waitcnt does
    // NOT invalidate caches, unlike __threadfence), then signal completion.
    __builtin_amdgcn_s_waitcnt(0);
    __syncthreads();
    if (t == 0) sLast = (atomicAdd(dctr, 1) == gridDim.x - 1) ? 1 : 0;
    __syncthreads();
    if (sLast) {
        // node_out gather (hh written by the previous kernel: safe to read)
        const int total = G * D_F;
        for (int i = t; i < total; i += 256) {
            int g = i >> 7;
            int c = i & (D_F - 1);
            out[i] = (float)hh[(size_t)nid[g] * D_F + c];
        }
        // loss: coherent RMW reads of the device-scope accumulators
        float p = 0.f;
        for (int g = t; g < G; g += 256) {
            float w = atomicAdd(&ew[g], 0.f);
            float v = atomicAdd(&ga[g], 0.f);
            p += (w != 0.f) ? v / w : 0.f;
        }
        #pragma unroll
        for (int m = 32; m > 0; m >>= 1) p += __shfl_xor(p, m);
        if ((t & 63) == 0) sred[t >> 6] = p;
        __syncthreads();
        if (t == 0)
            out[total] = (sred[0] + sred[1] + sred[2] + sred[3]) / (float)G;
    }
}

// ---------------------------------------------------------------------------
extern "C" void kernel_launch(void* const* d_in, const int* in_sizes, int n_in,
                              void* d_out, int out_size, void* d_ws, size_t ws_size,
                              hipStream_t stream) {
    const float* nodes     = (const float*)d_in[0];
    const float* edges     = (const float*)d_in[1];
    const int*   senders   = (const int*)d_in[2];
    const int*   receivers = (const int*)d_in[3];
    const int*   n_node    = (const int*)d_in[4];
    const int*   n_edge    = (const int*)d_in[5];
    const float* W1        = (const float*)d_in[6];
    const float* b1        = (const float*)d_in[7];
    const float* W2        = (const float*)d_in[8];
    const float* b2        = (const float*)d_in[9];

    const int N = in_sizes[0] / D_F;
    const int E = in_sizes[1];
    const int G = in_sizes[4];

    float* out = (float*)d_out;

    // workspace: hh f16 | W1T bf16 | W2T bf16 | ec | nid | ew | ga | dctr
    _Float16*       hh  = (_Float16*)d_ws;
    unsigned short* W1T = (unsigned short*)(hh + (size_t)N * D_F);
    unsigned short* W2T = W1T + (size_t)D_F * D_H;
    int*            ec  = (int*)(W2T + (size_t)D_F * D_H);
    int*            nid = ec + (G + 1);
    float*          ew  = (float*)(nid + G);
    float*          ga  = ew + G;
    int*            dctr = (int*)(ga + G);

    prep_kernel<<<(D_F * D_H + 255) / 256, 256, 0, stream>>>(
        W1, W2, n_node, n_edge, W1T, W2T, ec, nid, ew, ga, dctr, G, E);

    const int nblk = (N + 15) / 16;
    mlp_mfma_kernel<<<nblk, 512, 0, stream>>>(nodes, W1T, b1, W2T, b2, hh, N);

    const int ntiles = (E + 63) / 64;
    const int nblkE  = (ntiles + 3) / 4;
    edge_kernel<<<nblkE, 256, 0, stream>>>(hh, edges, senders, receivers, ec, nid,
                                           ew, ga, dctr, out, E, G);
}

// Round 12
// 140.745 us; speedup vs baseline: 1.1113x; 1.1113x over previous
//
#include <hip/hip_runtime.h>

#define D_F 128
#define D_H 512
#define SHS 520   // sH row stride (bf16 elems): 1040 B, 16B-aligned

typedef short v8s __attribute__((ext_vector_type(8)));
typedef float v4f __attribute__((ext_vector_type(4)));
typedef _Float16 v2h __attribute__((ext_vector_type(2)));

__device__ inline unsigned short f2bf(float f) {
    unsigned u = __float_as_uint(f);
    unsigned r = (u + 0x7fffu + ((u >> 16) & 1u)) >> 16;   // RNE
    return (unsigned short)r;
}
__device__ inline v2h bch(unsigned x) { return __builtin_bit_cast(v2h, x); }

// ---------------------------------------------------------------------------
// prep: weight conversion (all blocks) + init cumsums/zeros (block 0)
// ---------------------------------------------------------------------------
__global__ __launch_bounds__(256) void prep_kernel(
    const float* __restrict__ W1, const float* __restrict__ W2,
    const int* __restrict__ n_node, const int* __restrict__ n_edge,
    unsigned short* __restrict__ W1T, unsigned short* __restrict__ W2T,
    int* __restrict__ ec, int* __restrict__ nid,
    float* __restrict__ ew, float* __restrict__ ga, int G, int E)
{
    if (blockIdx.x == 0) {
        __shared__ int sne[512];
        __shared__ int snn[512];
        const int t = threadIdx.x;
        for (int g = t; g < G; g += 256) { sne[g] = n_edge[g]; snn[g] = n_node[g]; }
        __syncthreads();
        for (int g = t; g < G; g += 256) {
            int se = 0, sn = 0;
            for (int k = 0; k < g; ++k)  se += sne[k];
            for (int k = 0; k <= g; ++k) sn += snn[k];
            ec[g]  = se;
            nid[g] = sn - 1;
            ew[g] = 0.f;
            ga[g] = 0.f;
            if (g == G - 1) {
                int tot = se + sne[g];
                ec[G] = tot > E ? tot : E;
            }
        }
    }
    int i = blockIdx.x * 256 + threadIdx.x;
    if (i < D_F * D_H) {
        int n = i >> 7, k = i & (D_F - 1);        // W1T[n][k] = W1[k][n]
        W1T[i] = f2bf(W1[k * D_H + n]);
        int n2 = i >> 9, k2 = i & (D_H - 1);      // W2T[n2][k2] = W2[k2][n2]
        W2T[i] = f2bf(W2[k2 * D_F + n2]);
    }
}

// ---------------------------------------------------------------------------
// Fused MLP via MFMA (bf16 weights, fp16 output h): 16 rows / block, 8 waves
// splitting the n-dimension (5000 waves).
// ---------------------------------------------------------------------------
__global__ __launch_bounds__(512) void mlp_mfma_kernel(
    const float* __restrict__ nodes,
    const unsigned short* __restrict__ W1T, const float* __restrict__ b1,
    const unsigned short* __restrict__ W2T, const float* __restrict__ b2,
    _Float16* __restrict__ hh, int N)
{
    __shared__ unsigned short sH[16 * SHS];   // 16.6 KB

    const int t    = threadIdx.x;
    const int wave = t >> 6;        // 0..7
    const int lane = t & 63;
    const int li   = lane & 15;
    const int quad = lane >> 4;
    const int row0 = blockIdx.x * 16;

    // A fragments for GEMM1 (same 16 rows for all 8 waves; L1-served)
    v8s a1[4];
    {
        int r = min(row0 + li, N - 1);
        const float* xp = nodes + (size_t)r * D_F + quad * 8;
        #pragma unroll
        for (int ks = 0; ks < 4; ++ks) {
            float4 f0 = *(const float4*)(xp + ks * 32);
            float4 f1 = *(const float4*)(xp + ks * 32 + 4);
            v8s v;
            v[0] = (short)f2bf(f0.x); v[1] = (short)f2bf(f0.y);
            v[2] = (short)f2bf(f0.z); v[3] = (short)f2bf(f0.w);
            v[4] = (short)f2bf(f1.x); v[5] = (short)f2bf(f1.y);
            v[6] = (short)f2bf(f1.z); v[7] = (short)f2bf(f1.w);
            a1[ks] = v;
        }
    }

    // GEMM1: this wave covers hidden cols [wave*64, wave*64+64)
    #pragma unroll 2
    for (int jj = 0; jj < 4; ++jj) {
        const int n0 = (wave * 4 + jj) * 16;
        const unsigned short* wp = W1T + (size_t)(n0 + li) * D_F + quad * 8;
        v4f acc = {0.f, 0.f, 0.f, 0.f};
        #pragma unroll
        for (int ks = 0; ks < 4; ++ks) {
            v8s b = *(const v8s*)(wp + ks * 32);
            acc = __builtin_amdgcn_mfma_f32_16x16x32_bf16(a1[ks], b, acc, 0, 0, 0);
        }
        float bias = b1[n0 + li];
        #pragma unroll
        for (int r = 0; r < 4; ++r) {
            float hv = fmaxf(acc[r] + bias, 0.f);
            int m = quad * 4 + r;                 // C layout: row = quad*4+reg
            sH[m * SHS + n0 + li] = f2bf(hv);     // col = li
        }
    }
    __syncthreads();

    // A fragments for GEMM2 from LDS
    v8s aH[16];
    #pragma unroll
    for (int ks = 0; ks < 16; ++ks)
        aH[ks] = *(const v8s*)(sH + li * SHS + ks * 32 + quad * 8);

    // GEMM2: this wave covers output cols [wave*16, wave*16+16)
    {
        const int n0 = wave * 16;
        const unsigned short* wp = W2T + (size_t)(n0 + li) * D_H + quad * 8;
        v4f acc = {0.f, 0.f, 0.f, 0.f};
        #pragma unroll
        for (int kc = 0; kc < 2; ++kc) {
            v8s bb[8];
            #pragma unroll
            for (int u = 0; u < 8; ++u)
                bb[u] = *(const v8s*)(wp + (kc * 8 + u) * 32);
            #pragma unroll
            for (int u = 0; u < 8; ++u)
                acc = __builtin_amdgcn_mfma_f32_16x16x32_bf16(aH[kc * 8 + u], bb[u], acc, 0, 0, 0);
        }
        float bias = b2[n0 + li];
        #pragma unroll
        for (int r = 0; r < 4; ++r) {
            int grow = row0 + quad * 4 + r;
            if (grow < N)
                hh[(size_t)grow * D_F + n0 + li] = (_Float16)(acc[r] + bias);
        }
    }
}

// ---------------------------------------------------------------------------
// Edge stage: 512-thread blocks, 8 waves, ONE exact 64-edge tile per wave
// (10000 waves in 1250 blocks: max TLP, min per-block overhead). Lane l owns
// dims {2l,2l+1}; each gather covers ONE row (fully coalesced 256 B). __shfl
// broadcast, 16-edge batches. Per-lane accumulation; reduce at flush only.
// LDS-staged atomics. No device fence (r8 lesson: threadfence = L2 inval).
// ---------------------------------------------------------------------------
__global__ __launch_bounds__(512) void edge_kernel(
    const _Float16* __restrict__ hh, const float* __restrict__ wedge,
    const int* __restrict__ senders, const int* __restrict__ receivers,
    const int* __restrict__ ec,
    float* __restrict__ ew, float* __restrict__ ga,
    int E, int G)
{
    __shared__ int   sec[513];
    __shared__ float sga[512];
    __shared__ float sew[512];
    const int t = threadIdx.x;
    for (int i = t; i <= G; i += 512) sec[i] = ec[i];
    for (int i = t; i < G;  i += 512) { sga[i] = 0.f; sew[i] = 0.f; }
    __syncthreads();

    const unsigned* __restrict__ h32 = (const unsigned*)hh;   // row = 64 dwords
    const int lane = t & 63;
    const int wid  = blockIdx.x * 8 + (t >> 6);
    const int tb   = wid << 6;

    if (tb < E) {
        const int nt = min(64, E - tb);

        int gid;
        { int lo = 0, hi = G - 1;
          while (lo < hi) { int m = (lo + hi + 1) >> 1; if (sec[m] <= tb) lo = m; else hi = m - 1; }
          gid = lo; }

        const int ecl = min(tb + lane, E - 1);
        const bool vld = (tb + lane) < E;
        int   sv = __builtin_nontemporal_load(senders + ecl);
        int   rv = __builtin_nontemporal_load(receivers + ecl);
        float wv = vld ? __builtin_nontemporal_load(wedge + ecl) : 0.f;

        float accE = 0.f, accW = 0.f;

        if (nt == 64 && tb + 64 <= sec[gid + 1]) {
            // fast path: full tile in current segment
            #pragma unroll 1
            for (int i = 0; i < 64; i += 16) {
                unsigned a[16], b[16];
                int su[16], ru[16];
                #pragma unroll
                for (int u = 0; u < 16; ++u) {
                    su[u] = __shfl(sv, i + u);
                    ru[u] = __shfl(rv, i + u);
                }
                #pragma unroll
                for (int u = 0; u < 16; ++u) {
                    a[u] = h32[(unsigned)((su[u] << 6) | lane)];
                    b[u] = h32[(unsigned)((ru[u] << 6) | lane)];
                }
                #pragma unroll
                for (int u = 0; u < 16; ++u) {
                    float w = __shfl(wv, i + u);
                    v2h d  = bch(a[u]) - bch(b[u]);
                    float tt = __builtin_amdgcn_fdot2(d, d, 0.f, false);
                    accE = fmaf(w, tt, accE);
                }
            }
            accW = wv;   // own-lane weight; lane-sum = tile sum
            float rE = accE, rW = accW;
            #pragma unroll
            for (int m = 32; m > 0; m >>= 1) {
                rE += __shfl_xor(rE, m);
                rW += __shfl_xor(rW, m);
            }
            if (lane == 0) {
                atomicAdd(&sga[gid], rE);
                atomicAdd(&sew[gid], rW);
            }
        } else {
            // boundary/tail tile: per-edge with segment flushes
            for (int i = 0; i < nt; ++i) {
                int e = tb + i;
                while (e >= sec[gid + 1]) {
                    float rE = accE, rW = accW;
                    #pragma unroll
                    for (int m = 32; m > 0; m >>= 1) {
                        rE += __shfl_xor(rE, m);
                        rW += __shfl_xor(rW, m);
                    }
                    if (lane == 0 && (rE != 0.f || rW != 0.f)) {
                        atomicAdd(&sga[gid], rE);
                        atomicAdd(&sew[gid], rW);
                    }
                    accE = 0.f; accW = 0.f;
                    ++gid;
                }
                int   s = __shfl(sv, i);
                int   r = __shfl(rv, i);
                float w = __shfl(wv, i);
                unsigned a = h32[(unsigned)((s << 6) | lane)];
                unsigned b = h32[(unsigned)((r << 6) | lane)];
                v2h d = bch(a) - bch(b);
                float tt = __builtin_amdgcn_fdot2(d, d, 0.f, false);
                accE = fmaf(w, tt, accE);
                if (lane == 0) accW += w;
            }
            float rE = accE, rW = accW;
            #pragma unroll
            for (int m = 32; m > 0; m >>= 1) {
                rE += __shfl_xor(rE, m);
                rW += __shfl_xor(rW, m);
            }
            if (lane == 0 && (rE != 0.f || rW != 0.f)) {
                atomicAdd(&sga[gid], rE);
                atomicAdd(&sew[gid], rW);
            }
        }
    }

    __syncthreads();
    for (int g = t; g < G; g += 512) {
        float vg = sga[g], vw = sew[g];
        if (vg != 0.f || vw != 0.f) {
            atomicAdd(&ga[g], vg);
            atomicAdd(&ew[g], vw);
        }
    }
}

// ---------------------------------------------------------------------------
// Finalize: block g < G gathers node_out row; block G computes loss.
// ---------------------------------------------------------------------------
__global__ __launch_bounds__(128) void finalize_kernel(
    const _Float16* __restrict__ hh, const int* __restrict__ nid,
    const float* __restrict__ ew, const float* __restrict__ ga,
    float* __restrict__ out, int G)
{
    const int g = blockIdx.x;
    const int t = threadIdx.x;
    if (g < G) {
        int src = nid[g];
        out[(size_t)g * D_F + t] = (float)hh[(size_t)src * D_F + t];
    } else {
        float p = 0.f;
        for (int i = t; i < G; i += 128) {
            float w = ew[i];
            p += (w != 0.f) ? ga[i] / w : 0.f;
        }
        #pragma unroll
        for (int m = 32; m > 0; m >>= 1) p += __shfl_xor(p, m);
        __shared__ float sp[2];
        if ((t & 63) == 0) sp[t >> 6] = p;
        __syncthreads();
        if (t == 0) out[(size_t)G * D_F] = (sp[0] + sp[1]) / (float)G;
    }
}

// ---------------------------------------------------------------------------
extern "C" void kernel_launch(void* const* d_in, const int* in_sizes, int n_in,
                              void* d_out, int out_size, void* d_ws, size_t ws_size,
                              hipStream_t stream) {
    const float* nodes     = (const float*)d_in[0];
    const float* edges     = (const float*)d_in[1];
    const int*   senders   = (const int*)d_in[2];
    const int*   receivers = (const int*)d_in[3];
    const int*   n_node    = (const int*)d_in[4];
    const int*   n_edge    = (const int*)d_in[5];
    const float* W1        = (const float*)d_in[6];
    const float* b1        = (const float*)d_in[7];
    const float* W2        = (const float*)d_in[8];
    const float* b2        = (const float*)d_in[9];

    const int N = in_sizes[0] / D_F;
    const int E = in_sizes[1];
    const int G = in_sizes[4];

    float* out = (float*)d_out;

    // workspace: hh f16 | W1T bf16 | W2T bf16 | ec | nid | ew | ga
    _Float16*       hh  = (_Float16*)d_ws;
    unsigned short* W1T = (unsigned short*)(hh + (size_t)N * D_F);
    unsigned short* W2T = W1T + (size_t)D_F * D_H;
    int*            ec  = (int*)(W2T + (size_t)D_F * D_H);
    int*            nid = ec + (G + 1);
    float*          ew  = (float*)(nid + G);
    float*          ga  = ew + G;

    prep_kernel<<<(D_F * D_H + 255) / 256, 256, 0, stream>>>(
        W1, W2, n_node, n_edge, W1T, W2T, ec, nid, ew, ga, G, E);

    const int nblk = (N + 15) / 16;
    mlp_mfma_kernel<<<nblk, 512, 0, stream>>>(nodes, W1T, b1, W2T, b2, hh, N);

    const int ntiles = (E + 63) / 64;          // one exact 64-tile per wave
    const int nblkE  = (ntiles + 7) / 8;       // 8 waves per 512-thread block
    edge_kernel<<<nblkE, 512, 0, stream>>>(hh, edges, senders, receivers, ec,
                                           ew, ga, E, G);

    finalize_kernel<<<G + 1, 128, 0, stream>>>(hh, nid, ew, ga, out, G);
}

// Round 13
// 132.105 us; speedup vs baseline: 1.1840x; 1.0654x over previous
//
#include <hip/hip_runtime.h>

#define D_F 128
#define D_H 512
#define SHS 520   // sH row stride (bf16 elems): 1040 B, 16B-aligned

typedef short v8s __attribute__((ext_vector_type(8)));
typedef float v4f __attribute__((ext_vector_type(4)));
typedef _Float16 v2h __attribute__((ext_vector_type(2)));

__device__ inline unsigned short f2bf(float f) {
    unsigned u = __float_as_uint(f);
    unsigned r = (u + 0x7fffu + ((u >> 16) & 1u)) >> 16;   // RNE
    return (unsigned short)r;
}
__device__ inline v2h bch(unsigned x) { return __builtin_bit_cast(v2h, x); }

// ---------------------------------------------------------------------------
// prep: weight conversion (all blocks) + init cumsums/zeros (block 0)
// ---------------------------------------------------------------------------
__global__ __launch_bounds__(256) void prep_kernel(
    const float* __restrict__ W1, const float* __restrict__ W2,
    const int* __restrict__ n_node, const int* __restrict__ n_edge,
    unsigned short* __restrict__ W1T, unsigned short* __restrict__ W2T,
    int* __restrict__ ec, int* __restrict__ nid,
    float* __restrict__ ew, float* __restrict__ ga, int G, int E)
{
    if (blockIdx.x == 0) {
        __shared__ int sne[512];
        __shared__ int snn[512];
        const int t = threadIdx.x;
        for (int g = t; g < G; g += 256) { sne[g] = n_edge[g]; snn[g] = n_node[g]; }
        __syncthreads();
        for (int g = t; g < G; g += 256) {
            int se = 0, sn = 0;
            for (int k = 0; k < g; ++k)  se += sne[k];
            for (int k = 0; k <= g; ++k) sn += snn[k];
            ec[g]  = se;
            nid[g] = sn - 1;
            ew[g] = 0.f;
            ga[g] = 0.f;
            if (g == G - 1) {
                int tot = se + sne[g];
                ec[G] = tot > E ? tot : E;
            }
        }
    }
    int i = blockIdx.x * 256 + threadIdx.x;
    if (i < D_F * D_H) {
        int n = i >> 7, k = i & (D_F - 1);        // W1T[n][k] = W1[k][n]
        W1T[i] = f2bf(W1[k * D_H + n]);
        int n2 = i >> 9, k2 = i & (D_H - 1);      // W2T[n2][k2] = W2[k2][n2]
        W2T[i] = f2bf(W2[k2 * D_F + n2]);
    }
}

// ---------------------------------------------------------------------------
// Fused MLP via MFMA (bf16 weights, fp16 output h): 16 rows / block, 8 waves
// splitting the n-dimension (5000 waves).
// ---------------------------------------------------------------------------
__global__ __launch_bounds__(512) void mlp_mfma_kernel(
    const float* __restrict__ nodes,
    const unsigned short* __restrict__ W1T, const float* __restrict__ b1,
    const unsigned short* __restrict__ W2T, const float* __restrict__ b2,
    _Float16* __restrict__ hh, int N)
{
    __shared__ unsigned short sH[16 * SHS];   // 16.6 KB

    const int t    = threadIdx.x;
    const int wave = t >> 6;        // 0..7
    const int lane = t & 63;
    const int li   = lane & 15;
    const int quad = lane >> 4;
    const int row0 = blockIdx.x * 16;

    // A fragments for GEMM1 (same 16 rows for all 8 waves; L1-served)
    v8s a1[4];
    {
        int r = min(row0 + li, N - 1);
        const float* xp = nodes + (size_t)r * D_F + quad * 8;
        #pragma unroll
        for (int ks = 0; ks < 4; ++ks) {
            float4 f0 = *(const float4*)(xp + ks * 32);
            float4 f1 = *(const float4*)(xp + ks * 32 + 4);
            v8s v;
            v[0] = (short)f2bf(f0.x); v[1] = (short)f2bf(f0.y);
            v[2] = (short)f2bf(f0.z); v[3] = (short)f2bf(f0.w);
            v[4] = (short)f2bf(f1.x); v[5] = (short)f2bf(f1.y);
            v[6] = (short)f2bf(f1.z); v[7] = (short)f2bf(f1.w);
            a1[ks] = v;
        }
    }

    // GEMM1: this wave covers hidden cols [wave*64, wave*64+64)
    #pragma unroll 2
    for (int jj = 0; jj < 4; ++jj) {
        const int n0 = (wave * 4 + jj) * 16;
        const unsigned short* wp = W1T + (size_t)(n0 + li) * D_F + quad * 8;
        v4f acc = {0.f, 0.f, 0.f, 0.f};
        #pragma unroll
        for (int ks = 0; ks < 4; ++ks) {
            v8s b = *(const v8s*)(wp + ks * 32);
            acc = __builtin_amdgcn_mfma_f32_16x16x32_bf16(a1[ks], b, acc, 0, 0, 0);
        }
        float bias = b1[n0 + li];
        #pragma unroll
        for (int r = 0; r < 4; ++r) {
            float hv = fmaxf(acc[r] + bias, 0.f);
            int m = quad * 4 + r;                 // C layout: row = quad*4+reg
            sH[m * SHS + n0 + li] = f2bf(hv);     // col = li
        }
    }
    __syncthreads();

    // A fragments for GEMM2 from LDS
    v8s aH[16];
    #pragma unroll
    for (int ks = 0; ks < 16; ++ks)
        aH[ks] = *(const v8s*)(sH + li * SHS + ks * 32 + quad * 8);

    // GEMM2: this wave covers output cols [wave*16, wave*16+16)
    {
        const int n0 = wave * 16;
        const unsigned short* wp = W2T + (size_t)(n0 + li) * D_H + quad * 8;
        v4f acc = {0.f, 0.f, 0.f, 0.f};
        #pragma unroll
        for (int kc = 0; kc < 2; ++kc) {
            v8s bb[8];
            #pragma unroll
            for (int u = 0; u < 8; ++u)
                bb[u] = *(const v8s*)(wp + (kc * 8 + u) * 32);
            #pragma unroll
            for (int u = 0; u < 8; ++u)
                acc = __builtin_amdgcn_mfma_f32_16x16x32_bf16(aH[kc * 8 + u], bb[u], acc, 0, 0, 0);
        }
        float bias = b2[n0 + li];
        #pragma unroll
        for (int r = 0; r < 4; ++r) {
            int grow = row0 + quad * 4 + r;
            if (grow < N)
                hh[(size_t)grow * D_F + n0 + li] = (_Float16)(acc[r] + bias);
        }
    }
}

// ---------------------------------------------------------------------------
// Edge stage: 512-thread blocks, 8 waves, ONE exact 64-edge tile per wave.
// Indices/weights arrive via wave-uniform SCALAR loads (s_load through the
// constant cache -- no ds_bpermute, no VALU->SALU hazard). Each gather stays
// one fully-coalesced 256 B row per full-wave instruction (the r4/r12-proven
// shape). Weight is an SGPR operand of v_fma; accW is wave-uniform (no
// reduction). LDS-staged atomics; no device fence (r8: threadfence = L2 inval).
// ---------------------------------------------------------------------------
__global__ __launch_bounds__(512) void edge_kernel(
    const _Float16* __restrict__ hh, const float* __restrict__ wedge,
    const int* __restrict__ senders, const int* __restrict__ receivers,
    const int* __restrict__ ec,
    float* __restrict__ ew, float* __restrict__ ga,
    int E, int G)
{
    __shared__ int   sec[513];
    __shared__ float sga[512];
    __shared__ float sew[512];
    const int t = threadIdx.x;
    for (int i = t; i <= G; i += 512) sec[i] = ec[i];
    for (int i = t; i < G;  i += 512) { sga[i] = 0.f; sew[i] = 0.f; }
    __syncthreads();

    const unsigned* __restrict__ h32 = (const unsigned*)hh;   // row = 64 dwords
    const int lane = t & 63;
    const int tb   = (blockIdx.x * 8 + (t >> 6)) << 6;

    if (tb < E) {
        const int tbu = __builtin_amdgcn_readfirstlane(tb);   // uniform tile base
        const int nt  = min(64, E - tbu);

        int gid;
        { int lo = 0, hi = G - 1;
          while (lo < hi) { int m = (lo + hi + 1) >> 1; if (sec[m] <= tbu) lo = m; else hi = m - 1; }
          gid = lo; }

        // uniform pointers -> scalar loads
        const int*   __restrict__ sp = senders   + tbu;
        const int*   __restrict__ rp = receivers + tbu;
        const float* __restrict__ wp = wedge     + tbu;

        if (nt == 64 && tbu + 64 <= sec[gid + 1]) {
            // ---- fast path: full tile in one segment ----
            float accE = 0.f, accW = 0.f;     // accW uniform by construction
            #pragma unroll 1
            for (int i = 0; i < 64; i += 16) {
                unsigned a[16], b[16];
                #pragma unroll
                for (int u = 0; u < 16; ++u) {
                    int s = sp[i + u];                       // s_load (uniform)
                    int r = rp[i + u];                       // s_load (uniform)
                    a[u] = h32[(unsigned)((s << 6) | lane)]; // 1 row / instr
                    b[u] = h32[(unsigned)((r << 6) | lane)];
                }
                #pragma unroll
                for (int u = 0; u < 16; ++u) {
                    float w = wp[i + u];                     // s_load (uniform)
                    v2h d  = bch(a[u]) - bch(b[u]);
                    float tt = __builtin_amdgcn_fdot2(d, d, 0.f, false);
                    accE = fmaf(w, tt, accE);
                    accW += w;
                }
            }
            float rE = accE;
            #pragma unroll
            for (int m = 32; m > 0; m >>= 1) rE += __shfl_xor(rE, m);
            if (lane == 0) {
                atomicAdd(&sga[gid], rE);
                atomicAdd(&sew[gid], accW);
            }
        } else {
            // ---- slow path: per-edge with segment flushes (uniform loads) ----
            float accE = 0.f, accW = 0.f;
            for (int i = 0; i < nt; ++i) {
                int e = tbu + i;
                while (e >= sec[gid + 1]) {
                    float rE = accE;
                    #pragma unroll
                    for (int m = 32; m > 0; m >>= 1) rE += __shfl_xor(rE, m);
                    if (lane == 0 && (rE != 0.f || accW != 0.f)) {
                        atomicAdd(&sga[gid], rE);
                        atomicAdd(&sew[gid], accW);
                    }
                    accE = 0.f; accW = 0.f;
                    ++gid;
                }
                int   s = sp[i];
                int   r = rp[i];
                float w = wp[i];
                unsigned a = h32[(unsigned)((s << 6) | lane)];
                unsigned b = h32[(unsigned)((r << 6) | lane)];
                v2h d = bch(a) - bch(b);
                float tt = __builtin_amdgcn_fdot2(d, d, 0.f, false);
                accE = fmaf(w, tt, accE);
                accW += w;
            }
            float rE = accE;
            #pragma unroll
            for (int m = 32; m > 0; m >>= 1) rE += __shfl_xor(rE, m);
            if (lane == 0 && (rE != 0.f || accW != 0.f)) {
                atomicAdd(&sga[gid], rE);
                atomicAdd(&sew[gid], accW);
            }
        }
    }

    __syncthreads();
    for (int g = t; g < G; g += 512) {
        float vg = sga[g], vw = sew[g];
        if (vg != 0.f || vw != 0.f) {
            atomicAdd(&ga[g], vg);
            atomicAdd(&ew[g], vw);
        }
    }
}

// ---------------------------------------------------------------------------
// Finalize: block g < G gathers node_out row; block G computes loss.
// ---------------------------------------------------------------------------
__global__ __launch_bounds__(128) void finalize_kernel(
    const _Float16* __restrict__ hh, const int* __restrict__ nid,
    const float* __restrict__ ew, const float* __restrict__ ga,
    float* __restrict__ out, int G)
{
    const int g = blockIdx.x;
    const int t = threadIdx.x;
    if (g < G) {
        int src = nid[g];
        out[(size_t)g * D_F + t] = (float)hh[(size_t)src * D_F + t];
    } else {
        float p = 0.f;
        for (int i = t; i < G; i += 128) {
            float w = ew[i];
            p += (w != 0.f) ? ga[i] / w : 0.f;
        }
        #pragma unroll
        for (int m = 32; m > 0; m >>= 1) p += __shfl_xor(p, m);
        __shared__ float sp[2];
        if ((t & 63) == 0) sp[t >> 6] = p;
        __syncthreads();
        if (t == 0) out[(size_t)G * D_F] = (sp[0] + sp[1]) / (float)G;
    }
}

// ---------------------------------------------------------------------------
extern "C" void kernel_launch(void* const* d_in, const int* in_sizes, int n_in,
                              void* d_out, int out_size, void* d_ws, size_t ws_size,
                              hipStream_t stream) {
    const float* nodes     = (const float*)d_in[0];
    const float* edges     = (const float*)d_in[1];
    const int*   senders   = (const int*)d_in[2];
    const int*   receivers = (const int*)d_in[3];
    const int*   n_node    = (const int*)d_in[4];
    const int*   n_edge    = (const int*)d_in[5];
    const float* W1        = (const float*)d_in[6];
    const float* b1        = (const float*)d_in[7];
    const float* W2        = (const float*)d_in[8];
    const float* b2        = (const float*)d_in[9];

    const int N = in_sizes[0] / D_F;
    const int E = in_sizes[1];
    const int G = in_sizes[4];

    float* out = (float*)d_out;

    // workspace: hh f16 | W1T bf16 | W2T bf16 | ec | nid | ew | ga
    _Float16*       hh  = (_Float16*)d_ws;
    unsigned short* W1T = (unsigned short*)(hh + (size_t)N * D_F);
    unsigned short* W2T = W1T + (size_t)D_F * D_H;
    int*            ec  = (int*)(W2T + (size_t)D_F * D_H);
    int*            nid = ec + (G + 1);
    float*          ew  = (float*)(nid + G);
    float*          ga  = ew + G;

    prep_kernel<<<(D_F * D_H + 255) / 256, 256, 0, stream>>>(
        W1, W2, n_node, n_edge, W1T, W2T, ec, nid, ew, ga, G, E);

    const int nblk = (N + 15) / 16;
    mlp_mfma_kernel<<<nblk, 512, 0, stream>>>(nodes, W1T, b1, W2T, b2, hh, N);

    const int ntiles = (E + 63) / 64;          // one exact 64-tile per wave
    const int nblkE  = (ntiles + 7) / 8;       // 8 waves per 512-thread block
    edge_kernel<<<nblkE, 512, 0, stream>>>(hh, edges, senders, receivers, ec,
                                           ew, ga, E, G);

    finalize_kernel<<<G + 1, 128, 0, stream>>>(hh, nid, ew, ga, out, G);
}

// Round 14
// 131.685 us; speedup vs baseline: 1.1878x; 1.0032x over previous
//
#include <hip/hip_runtime.h>

#define D_F 128
#define D_H 512
#define SHS 520   // sH row stride (bf16 elems): 1040 B, 16B-aligned

typedef short v8s __attribute__((ext_vector_type(8)));
typedef float v4f __attribute__((ext_vector_type(4)));
typedef _Float16 v2h __attribute__((ext_vector_type(2)));

__device__ inline unsigned short f2bf(float f) {
    unsigned u = __float_as_uint(f);
    unsigned r = (u + 0x7fffu + ((u >> 16) & 1u)) >> 16;   // RNE
    return (unsigned short)r;
}
__device__ inline v2h bch(unsigned x) { return __builtin_bit_cast(v2h, x); }

// ---------------------------------------------------------------------------
// prep: weight conversion (all blocks) + init cumsums/zeros (block 0)
// ---------------------------------------------------------------------------
__global__ __launch_bounds__(256) void prep_kernel(
    const float* __restrict__ W1, const float* __restrict__ W2,
    const int* __restrict__ n_node, const int* __restrict__ n_edge,
    unsigned short* __restrict__ W1T, unsigned short* __restrict__ W2T,
    int* __restrict__ ec, int* __restrict__ nid,
    float* __restrict__ ew, float* __restrict__ ga, int G, int E)
{
    if (blockIdx.x == 0) {
        __shared__ int sne[512];
        __shared__ int snn[512];
        const int t = threadIdx.x;
        for (int g = t; g < G; g += 256) { sne[g] = n_edge[g]; snn[g] = n_node[g]; }
        __syncthreads();
        for (int g = t; g < G; g += 256) {
            int se = 0, sn = 0;
            for (int k = 0; k < g; ++k)  se += sne[k];
            for (int k = 0; k <= g; ++k) sn += snn[k];
            ec[g]  = se;
            nid[g] = sn - 1;
            ew[g] = 0.f;
            ga[g] = 0.f;
            if (g == G - 1) {
                int tot = se + sne[g];
                ec[G] = tot > E ? tot : E;
            }
        }
    }
    int i = blockIdx.x * 256 + threadIdx.x;
    if (i < D_F * D_H) {
        int n = i >> 7, k = i & (D_F - 1);        // W1T[n][k] = W1[k][n]
        W1T[i] = f2bf(W1[k * D_H + n]);
        int n2 = i >> 9, k2 = i & (D_H - 1);      // W2T[n2][k2] = W2[k2][n2]
        W2T[i] = f2bf(W2[k2 * D_F + n2]);
    }
}

// ---------------------------------------------------------------------------
// Fused MLP via MFMA (bf16 weights, fp16 output h): 16 rows / block, 8 waves
// splitting the n-dimension (5000 waves).
// ---------------------------------------------------------------------------
__global__ __launch_bounds__(512) void mlp_mfma_kernel(
    const float* __restrict__ nodes,
    const unsigned short* __restrict__ W1T, const float* __restrict__ b1,
    const unsigned short* __restrict__ W2T, const float* __restrict__ b2,
    _Float16* __restrict__ hh, int N)
{
    __shared__ unsigned short sH[16 * SHS];   // 16.6 KB

    const int t    = threadIdx.x;
    const int wave = t >> 6;        // 0..7
    const int lane = t & 63;
    const int li   = lane & 15;
    const int quad = lane >> 4;
    const int row0 = blockIdx.x * 16;

    // A fragments for GEMM1 (same 16 rows for all 8 waves; L1-served)
    v8s a1[4];
    {
        int r = min(row0 + li, N - 1);
        const float* xp = nodes + (size_t)r * D_F + quad * 8;
        #pragma unroll
        for (int ks = 0; ks < 4; ++ks) {
            float4 f0 = *(const float4*)(xp + ks * 32);
            float4 f1 = *(const float4*)(xp + ks * 32 + 4);
            v8s v;
            v[0] = (short)f2bf(f0.x); v[1] = (short)f2bf(f0.y);
            v[2] = (short)f2bf(f0.z); v[3] = (short)f2bf(f0.w);
            v[4] = (short)f2bf(f1.x); v[5] = (short)f2bf(f1.y);
            v[6] = (short)f2bf(f1.z); v[7] = (short)f2bf(f1.w);
            a1[ks] = v;
        }
    }

    // GEMM1: this wave covers hidden cols [wave*64, wave*64+64)
    #pragma unroll 2
    for (int jj = 0; jj < 4; ++jj) {
        const int n0 = (wave * 4 + jj) * 16;
        const unsigned short* wp = W1T + (size_t)(n0 + li) * D_F + quad * 8;
        v4f acc = {0.f, 0.f, 0.f, 0.f};
        #pragma unroll
        for (int ks = 0; ks < 4; ++ks) {
            v8s b = *(const v8s*)(wp + ks * 32);
            acc = __builtin_amdgcn_mfma_f32_16x16x32_bf16(a1[ks], b, acc, 0, 0, 0);
        }
        float bias = b1[n0 + li];
        #pragma unroll
        for (int r = 0; r < 4; ++r) {
            float hv = fmaxf(acc[r] + bias, 0.f);
            int m = quad * 4 + r;                 // C layout: row = quad*4+reg
            sH[m * SHS + n0 + li] = f2bf(hv);     // col = li
        }
    }
    __syncthreads();

    // A fragments for GEMM2 from LDS
    v8s aH[16];
    #pragma unroll
    for (int ks = 0; ks < 16; ++ks)
        aH[ks] = *(const v8s*)(sH + li * SHS + ks * 32 + quad * 8);

    // GEMM2: this wave covers output cols [wave*16, wave*16+16)
    {
        const int n0 = wave * 16;
        const unsigned short* wp = W2T + (size_t)(n0 + li) * D_H + quad * 8;
        v4f acc = {0.f, 0.f, 0.f, 0.f};
        #pragma unroll
        for (int kc = 0; kc < 2; ++kc) {
            v8s bb[8];
            #pragma unroll
            for (int u = 0; u < 8; ++u)
                bb[u] = *(const v8s*)(wp + (kc * 8 + u) * 32);
            #pragma unroll
            for (int u = 0; u < 8; ++u)
                acc = __builtin_amdgcn_mfma_f32_16x16x32_bf16(aH[kc * 8 + u], bb[u], acc, 0, 0, 0);
        }
        float bias = b2[n0 + li];
        #pragma unroll
        for (int r = 0; r < 4; ++r) {
            int grow = row0 + quad * 4 + r;
            if (grow < N)
                hh[(size_t)grow * D_F + n0 + li] = (_Float16)(acc[r] + bias);
        }
    }
}

// ---------------------------------------------------------------------------
// Edge stage: 512-thread blocks, 8 waves, ONE exact 64-edge tile per wave.
// Scalar-loaded (constant-cache) indices/weights; one fully-coalesced 256 B
// row per full-wave gather instruction. 32-edge batches: 64 gathers in
// flight (~vmcnt queue depth) halve the drain boundaries per tile vs r13's
// 16-edge batches. LDS-staged atomics; no device fence (r8: = L2 inval).
// ---------------------------------------------------------------------------
__global__ __launch_bounds__(512) void edge_kernel(
    const _Float16* __restrict__ hh, const float* __restrict__ wedge,
    const int* __restrict__ senders, const int* __restrict__ receivers,
    const int* __restrict__ ec,
    float* __restrict__ ew, float* __restrict__ ga,
    int E, int G)
{
    __shared__ int   sec[513];
    __shared__ float sga[512];
    __shared__ float sew[512];
    const int t = threadIdx.x;
    for (int i = t; i <= G; i += 512) sec[i] = ec[i];
    for (int i = t; i < G;  i += 512) { sga[i] = 0.f; sew[i] = 0.f; }
    __syncthreads();

    const unsigned* __restrict__ h32 = (const unsigned*)hh;   // row = 64 dwords
    const int lane = t & 63;
    const int tb   = (blockIdx.x * 8 + (t >> 6)) << 6;

    if (tb < E) {
        const int tbu = __builtin_amdgcn_readfirstlane(tb);   // uniform tile base
        const int nt  = min(64, E - tbu);

        int gid;
        { int lo = 0, hi = G - 1;
          while (lo < hi) { int m = (lo + hi + 1) >> 1; if (sec[m] <= tbu) lo = m; else hi = m - 1; }
          gid = lo; }

        // uniform pointers -> scalar loads
        const int*   __restrict__ sp = senders   + tbu;
        const int*   __restrict__ rp = receivers + tbu;
        const float* __restrict__ wp = wedge     + tbu;

        if (nt == 64 && tbu + 64 <= sec[gid + 1]) {
            // ---- fast path: full tile in one segment; 32-edge batches ----
            float accE = 0.f, accW = 0.f;     // accW uniform by construction
            #pragma unroll 1
            for (int i = 0; i < 64; i += 32) {
                unsigned a[32], b[32];
                #pragma unroll
                for (int u = 0; u < 32; ++u) {
                    int s = sp[i + u];                       // s_load (uniform)
                    int r = rp[i + u];                       // s_load (uniform)
                    a[u] = h32[(unsigned)((s << 6) | lane)]; // 1 row / instr
                    b[u] = h32[(unsigned)((r << 6) | lane)];
                }
                #pragma unroll
                for (int u = 0; u < 32; ++u) {
                    float w = wp[i + u];                     // s_load (uniform)
                    v2h d  = bch(a[u]) - bch(b[u]);
                    float tt = __builtin_amdgcn_fdot2(d, d, 0.f, false);
                    accE = fmaf(w, tt, accE);
                    accW += w;
                }
            }
            float rE = accE;
            #pragma unroll
            for (int m = 32; m > 0; m >>= 1) rE += __shfl_xor(rE, m);
            if (lane == 0) {
                atomicAdd(&sga[gid], rE);
                atomicAdd(&sew[gid], accW);
            }
        } else {
            // ---- slow path: per-edge with segment flushes (uniform loads) ----
            float accE = 0.f, accW = 0.f;
            for (int i = 0; i < nt; ++i) {
                int e = tbu + i;
                while (e >= sec[gid + 1]) {
                    float rE = accE;
                    #pragma unroll
                    for (int m = 32; m > 0; m >>= 1) rE += __shfl_xor(rE, m);
                    if (lane == 0 && (rE != 0.f || accW != 0.f)) {
                        atomicAdd(&sga[gid], rE);
                        atomicAdd(&sew[gid], accW);
                    }
                    accE = 0.f; accW = 0.f;
                    ++gid;
                }
                int   s = sp[i];
                int   r = rp[i];
                float w = wp[i];
                unsigned a = h32[(unsigned)((s << 6) | lane)];
                unsigned b = h32[(unsigned)((r << 6) | lane)];
                v2h d = bch(a) - bch(b);
                float tt = __builtin_amdgcn_fdot2(d, d, 0.f, false);
                accE = fmaf(w, tt, accE);
                accW += w;
            }
            float rE = accE;
            #pragma unroll
            for (int m = 32; m > 0; m >>= 1) rE += __shfl_xor(rE, m);
            if (lane == 0 && (rE != 0.f || accW != 0.f)) {
                atomicAdd(&sga[gid], rE);
                atomicAdd(&sew[gid], accW);
            }
        }
    }

    __syncthreads();
    for (int g = t; g < G; g += 512) {
        float vg = sga[g], vw = sew[g];
        if (vg != 0.f || vw != 0.f) {
            atomicAdd(&ga[g], vg);
            atomicAdd(&ew[g], vw);
        }
    }
}

// ---------------------------------------------------------------------------
// Finalize: block g < G gathers node_out row; block G computes loss.
// ---------------------------------------------------------------------------
__global__ __launch_bounds__(128) void finalize_kernel(
    const _Float16* __restrict__ hh, const int* __restrict__ nid,
    const float* __restrict__ ew, const float* __restrict__ ga,
    float* __restrict__ out, int G)
{
    const int g = blockIdx.x;
    const int t = threadIdx.x;
    if (g < G) {
        int src = nid[g];
        out[(size_t)g * D_F + t] = (float)hh[(size_t)src * D_F + t];
    } else {
        float p = 0.f;
        for (int i = t; i < G; i += 128) {
            float w = ew[i];
            p += (w != 0.f) ? ga[i] / w : 0.f;
        }
        #pragma unroll
        for (int m = 32; m > 0; m >>= 1) p += __shfl_xor(p, m);
        __shared__ float sp[2];
        if ((t & 63) == 0) sp[t >> 6] = p;
        __syncthreads();
        if (t == 0) out[(size_t)G * D_F] = (sp[0] + sp[1]) / (float)G;
    }
}

// ---------------------------------------------------------------------------
extern "C" void kernel_launch(void* const* d_in, const int* in_sizes, int n_in,
                              void* d_out, int out_size, void* d_ws, size_t ws_size,
                              hipStream_t stream) {
    const float* nodes     = (const float*)d_in[0];
    const float* edges     = (const float*)d_in[1];
    const int*   senders   = (const int*)d_in[2];
    const int*   receivers = (const int*)d_in[3];
    const int*   n_node    = (const int*)d_in[4];
    const int*   n_edge    = (const int*)d_in[5];
    const float* W1        = (const float*)d_in[6];
    const float* b1        = (const float*)d_in[7];
    const float* W2        = (const float*)d_in[8];
    const float* b2        = (const float*)d_in[9];

    const int N = in_sizes[0] / D_F;
    const int E = in_sizes[1];
    const int G = in_sizes[4];

    float* out = (float*)d_out;

    // workspace: hh f16 | W1T bf16 | W2T bf16 | ec | nid | ew | ga
    _Float16*       hh  = (_Float16*)d_ws;
    unsigned short* W1T = (unsigned short*)(hh + (size_t)N * D_F);
    unsigned short* W2T = W1T + (size_t)D_F * D_H;
    int*            ec  = (int*)(W2T + (size_t)D_F * D_H);
    int*            nid = ec + (G + 1);
    float*          ew  = (float*)(nid + G);
    float*          ga  = ew + G;

    prep_kernel<<<(D_F * D_H + 255) / 256, 256, 0, stream>>>(
        W1, W2, n_node, n_edge, W1T, W2T, ec, nid, ew, ga, G, E);

    const int nblk = (N + 15) / 16;
    mlp_mfma_kernel<<<nblk, 512, 0, stream>>>(nodes, W1T, b1, W2T, b2, hh, N);

    const int ntiles = (E + 63) / 64;          // one exact 64-tile per wave
    const int nblkE  = (ntiles + 7) / 8;       // 8 waves per 512-thread block
    edge_kernel<<<nblkE, 512, 0, stream>>>(hh, edges, senders, receivers, ec,
                                           ew, ga, E, G);

    finalize_kernel<<<G + 1, 128, 0, stream>>>(hh, nid, ew, ga, out, G);
}